// Round 1
// 1470.407 us; speedup vs baseline: 1.2291x; 1.2291x over previous
//
#include <hip/hip_runtime.h>
#include <math.h>

// Problem constants (EnhancedVectorQuantizer): inputs (16,4096,256) f32, emb (2048,256) f32
#define NROWS  65536
#define DIM    256
#define KCODES 2048

#define Q_OFF  16777216   // NROWS*DIM; d_out layout: [0,Q_OFF) quantized_st, [Q_OFF]=loss, [Q_OFF+1]=perplexity, [Q_OFF+2..) idx as f32

// workspace byte offsets (total 294912 B)
#define WS_C      0        // 2048 f32  ||e_k||^2
#define WS_INV    8192     // 2048 f32  1/max(rownorm,1e-12)
#define WS_COUNTS 16384    // 2048 u32
#define WS_SUMS   24576    // 3 doubles: [0]=mse_sum [1]=l2_sum [2]=orth_sum
#define WS_X2     32768    // 65536 f32 ||x_n||^2 (replaces idx_ws; gather reads idx from out)

typedef __attribute__((address_space(1))) const void gvoid_t;
typedef __attribute__((address_space(3))) void lvoid_t;

// ---------------- init: zero accumulators (ws is poisoned 0xAA every launch) ----------------
__global__ void vq_init_kernel(unsigned* __restrict__ counts, double* __restrict__ sums) {
    int t = threadIdx.x;
    for (int k = t; k < KCODES; k += 256) counts[k] = 0u;
    if (t < 3) sums[t] = 0.0;
}

// ---------------- prep: c[k]=||e_k||^2, inv rownorm, l2 sum ----------------
__global__ void vq_prep_kernel(const float* __restrict__ emb, float* __restrict__ c,
                               float* __restrict__ invn, double* __restrict__ sums) {
    int k = blockIdx.x;
    int lane = threadIdx.x;                       // 64 lanes
    float4 v = ((const float4*)(emb + (size_t)k * DIM))[lane];
    float s = v.x * v.x + v.y * v.y + v.z * v.z + v.w * v.w;
    #pragma unroll
    for (int off = 32; off > 0; off >>= 1) s += __shfl_down(s, off, 64);
    if (lane == 0) {
        c[k] = s;
        float rn = sqrtf(s);
        invn[k] = 1.0f / fmaxf(rn, 1e-12f);
        atomicAdd(&sums[1], (double)rn);
    }
}

// ---------------- x2: per-row ||x||^2, serial float4 chain (bit-identical to ref order) ----------------
__global__ void vq_x2_kernel(const float* __restrict__ x, float* __restrict__ x2g) {
    int row = blockIdx.x * 256 + threadIdx.x;
    const float4* xr = (const float4*)(x + (size_t)row * DIM);
    float s = 0.f;
    for (int d4 = 0; d4 < DIM / 4; ++d4) {
        float4 v = xr[d4];
        s += v.x * v.x; s += v.y * v.y; s += v.z * v.z; s += v.w * v.w;
    }
    x2g[row] = s;
}

// ---------------- argmin: A-resident LDS + streamed-B fp32 distance GEMM + argmin ----------------
// Round-7 theory: the 4x4 register tile was LDS-read-pipe bound (8 ds_read_b128 per
// 64 FMAs -> 6.7e7 ds_reads, ~1310us floor vs 437us FMA floor; measured 1675us with
// 1.35e8 conflict cycles). Fix: 8x8 per-thread tile (16 reads per 256 FMAs), with a
// thread map that makes LDS conflict-free WITHOUT swizzle:
//   threads = 32 tx (codes, strided k = kt + tx + 32i) x 8 ty (rows, ty*8+j)
//   A reads: per instr only 2 distinct ty per wave -> 2 addresses, 32-lane broadcast
//            + 2-way alias = free (m136). So A stays LINEAR [64][256] -> DMA dest linear.
//   B chunk layout [dim-group g][256 codes][float4]: a b-read instr = 32 consecutive
//            16B slots = perfectly bank-balanced.
// LDS = A 64KB + B 2x8KB = 80KB -> 2 blocks/CU, 2 waves/EU (waves_per_eu(2,2)).
// acc 64 + a 32 + b 32 regs; budget <256 so no spill at 2 waves/EU.
// Accumulation chain per (row,code) unchanged vs round-6 (ascending 4-dim quads,
// acc += (ax*bx + ay*by + az*bz + aw*bw), reset per kt-tile) -> bit-identical.
// Explicit s_waitcnt(0) before each barrier (round-6 race fix, proven).
#define BM 64

__global__ __launch_bounds__(256)
__attribute__((amdgpu_waves_per_eu(2, 2)))
void vq_argmin_kernel(const float* __restrict__ x, const float* __restrict__ emb,
                      const float* __restrict__ c, const float* __restrict__ x2g,
                      float* __restrict__ idx_f, unsigned* __restrict__ counts) {
    extern __shared__ float smem[];          // 81920 B
    float* Asl = smem;                       // 16384 floats (64 KB), linear [64][256]
    float* Bsl = smem + 16384;               // 4096 floats (2 bufs x 2048), buf = [g:2][code:256][4]

    const int tid  = threadIdx.x;
    const int tx   = tid & 31, ty = tid >> 5;
    const int wave = tid >> 6, lane = tid & 63;
    const int row0 = blockIdx.x * BM;

    const float4* x4 = (const float4*)x;
    const float4* e4 = (const float4*)emb;

    // ---- A DMA (once): 16 rows per wave, one 1KB row per instr, linear dest ----
    #pragma unroll
    for (int q = 0; q < 16; ++q) {
        int r = wave * 16 + q;
        __builtin_amdgcn_global_load_lds(
            (gvoid_t*)(x4 + ((size_t)(row0 + r) * 64 + lane)),
            (lvoid_t*)(Asl + r * 256), 16, 0, 0);
    }
    // ---- B DMA step 0 (kt=0, dims [0,8)) ----
    {
        #pragma unroll
        for (int q = 0; q < 2; ++q) {
            int idx = wave * 2 + q;              // 0..7
            int g = idx >> 2, rblk = idx & 3;
            int r = rblk * 64 + lane;            // code 0..255
            __builtin_amdgcn_global_load_lds(
                (gvoid_t*)(e4 + ((size_t)r * 64 + g)),
                (lvoid_t*)(Bsl + g * 1024 + rblk * 256), 16, 0, 0);
        }
    }

    // per-row ||x||^2 from precomputed global (same values as inline chain)
    float x2r[8];
    #pragma unroll
    for (int j = 0; j < 8; ++j) x2r[j] = x2g[row0 + ty * 8 + j];

    __builtin_amdgcn_s_waitcnt(0);           // DMA landed in LDS
    __syncthreads();

    float best[8]; int bidx[8];
    #pragma unroll
    for (int j = 0; j < 8; ++j) { best[j] = 3.4e38f; bidx[j] = 0; }

    float acc[8][8];
    #pragma unroll
    for (int j = 0; j < 8; ++j)
        #pragma unroll
        for (int i = 0; i < 8; ++i) acc[j][i] = 0.f;

    const float4* A4 = (const float4*)Asl;
    const float4* B4 = (const float4*)Bsl;

    // 256 steps = 8 kt-tiles (256 codes) x 32 dim-chunks (8 dims)
    for (int s = 0; s < 256; ++s) {
        int dc = s & 31;

        // async DMA of next B chunk into the other buffer
        if (s < 255) {
            int sn   = s + 1;
            int dcn  = sn & 31;
            int ktn  = (sn >> 5) << 8;           // code-tile base row
            int d4n  = dcn << 1;                 // dim offset in float4 units
            float* Bd = Bsl + (sn & 1) * 2048;
            #pragma unroll
            for (int q = 0; q < 2; ++q) {
                int idx = wave * 2 + q;
                int g = idx >> 2, rblk = idx & 3;
                int r = rblk * 64 + lane;
                __builtin_amdgcn_global_load_lds(
                    (gvoid_t*)(e4 + ((size_t)(ktn + r) * 64 + d4n + g)),
                    (lvoid_t*)(Bd + g * 1024 + rblk * 256), 16, 0, 0);
            }
        }

        // compute this 8-dim chunk; dims ascending -> ref-identical chain
        {
            int abase = ty * 512 + (dc << 1);    // (ty*8)*64 + dc*2, float4 units
            int bbase = (s & 1) * 512 + tx;      // float4 units
            #pragma unroll
            for (int g = 0; g < 2; ++g) {
                float4 a[8], b[8];
                #pragma unroll
                for (int j = 0; j < 8; ++j) a[j] = A4[abase + j * 64 + g];
                #pragma unroll
                for (int i = 0; i < 8; ++i) b[i] = B4[bbase + g * 256 + i * 32];
                #pragma unroll
                for (int j = 0; j < 8; ++j)
                    #pragma unroll
                    for (int i = 0; i < 8; ++i)
                        acc[j][i] += a[j].x * b[i].x + a[j].y * b[i].y
                                   + a[j].z * b[i].z + a[j].w * b[i].w;
            }
        }

        if (dc == 31) {                          // full D done for this kt tile: fold argmin
            int kt = (s >> 5) << 8;
            #pragma unroll
            for (int i = 0; i < 8; ++i) {
                int k = kt + tx + 32 * i;        // ascending in i -> lowest-index tie win
                float ck = c[k];
                #pragma unroll
                for (int j = 0; j < 8; ++j) {
                    float t = x2r[j] + ck;               // matches reference eval order
                    float dst = t - 2.0f * acc[j][i];    // *2 exact
                    if (dst < best[j]) { best[j] = dst; bidx[j] = k; }
                }
            }
            #pragma unroll
            for (int j = 0; j < 8; ++j)
                #pragma unroll
                for (int i = 0; i < 8; ++i) acc[j][i] = 0.f;
        }

        __builtin_amdgcn_s_waitcnt(0);           // next-B DMA landed; this buf's reads done
        __syncthreads();
    }

    // final reduction: reuse Asl (behind the loop's last barrier). [64][33] padded.
    float* redv = Asl;
    int*   redi = (int*)(Asl + 2112);
    #pragma unroll
    for (int j = 0; j < 8; ++j) {
        int r = ty * 8 + j;
        redv[r * 33 + tx] = best[j];
        redi[r * 33 + tx] = bidx[j];
    }
    __builtin_amdgcn_s_waitcnt(0);
    __syncthreads();
    if (tid < BM) {
        float bv = redv[tid * 33]; int bi = redi[tid * 33];
        for (int t = 1; t < 32; ++t) {
            float v = redv[tid * 33 + t]; int ii = redi[tid * 33 + t];
            if (v < bv || (v == bv && ii < bi)) { bv = v; bi = ii; }  // ties -> lowest index
        }
        idx_f[row0 + tid] = (float)bi;
        atomicAdd(&counts[bi], 1u);
    }
}

// ---------------- gather: quantized_st = x + (e - x) (matches ST rounding), MSE sum ----------------
__global__ void vq_gather_kernel(const float* __restrict__ x, const float* __restrict__ emb,
                                 const float* __restrict__ idx_f, float* __restrict__ outq,
                                 double* __restrict__ sums) {
    __shared__ float red[256];
    int tid = threadIdx.x;
    int q = blockIdx.x * 256 + tid;        // float4 index, 4194304 total
    int n = q >> 6;
    int d4 = (q & 63) << 2;
    int k = (int)idx_f[n];                 // small ints stored exactly in f32
    float4 e  = *(const float4*)(emb + (size_t)k * DIM + d4);
    float4 xv = *(const float4*)(x + ((size_t)n * DIM + d4));
    float d0 = e.x - xv.x, d1 = e.y - xv.y, d2 = e.z - xv.z, d3 = e.w - xv.w;
    float4 o;
    o.x = xv.x + d0; o.y = xv.y + d1; o.z = xv.z + d2; o.w = xv.w + d3;
    *(float4*)(outq + (size_t)q * 4) = o;
    red[tid] = d0 * d0 + d1 * d1 + d2 * d2 + d3 * d3;
    __syncthreads();
    for (int off = 128; off > 0; off >>= 1) {
        if (tid < off) red[tid] += red[tid + off];
        __syncthreads();
    }
    if (tid == 0) atomicAdd(&sums[0], (double)red[0]);
}

// ---------------- sim: sum |off-diagonal cosine| ----------------
#define SPAD 68
__global__ __launch_bounds__(256)
void vq_sim_kernel(const float* __restrict__ emb, const float* __restrict__ invn,
                   double* __restrict__ sums) {
    __shared__ float Ai[64][SPAD];
    __shared__ float Bj[64][SPAD];
    int bi = blockIdx.x >> 5;
    int bj = blockIdx.x & 31;
    int tid = threadIdx.x;
    int tx = tid & 15, ty = tid >> 4;

    float acc[4][4];
    #pragma unroll
    for (int j = 0; j < 4; ++j)
        #pragma unroll
        for (int i = 0; i < 4; ++i) acc[j][i] = 0.f;

    for (int dc = 0; dc < DIM; dc += 64) {
        #pragma unroll
        for (int rr = 0; rr < 4; ++rr) {
            int row = rr * 16 + ty;
            int col = tx * 4;
            int ga = bi * 64 + row, gb = bj * 64 + row;
            float4 a = *(const float4*)(emb + (size_t)ga * DIM + dc + col);
            float4 b = *(const float4*)(emb + (size_t)gb * DIM + dc + col);
            float sa = invn[ga], sb = invn[gb];
            Ai[row][col + 0] = a.x * sa; Ai[row][col + 1] = a.y * sa;
            Ai[row][col + 2] = a.z * sa; Ai[row][col + 3] = a.w * sa;
            Bj[row][col + 0] = b.x * sb; Bj[row][col + 1] = b.y * sb;
            Bj[row][col + 2] = b.z * sb; Bj[row][col + 3] = b.w * sb;
        }
        __syncthreads();
        for (int d = 0; d < 64; d += 4) {
            float4 a[4], b[4];
            #pragma unroll
            for (int j = 0; j < 4; ++j) a[j] = *(const float4*)&Ai[ty * 4 + j][d];
            #pragma unroll
            for (int i = 0; i < 4; ++i) b[i] = *(const float4*)&Bj[tx * 4 + i][d];
            #pragma unroll
            for (int j = 0; j < 4; ++j)
                #pragma unroll
                for (int i = 0; i < 4; ++i)
                    acc[j][i] += a[j].x * b[i].x + a[j].y * b[i].y
                               + a[j].z * b[i].z + a[j].w * b[i].w;
        }
        __syncthreads();
    }
    float s = 0.f;
    #pragma unroll
    for (int j = 0; j < 4; ++j)
        #pragma unroll
        for (int i = 0; i < 4; ++i) {
            int gi = bi * 64 + ty * 4 + j;
            int gj = bj * 64 + tx * 4 + i;
            if (gi != gj) s += fabsf(acc[j][i]);
        }
    float* red = &Ai[0][0];
    red[tid] = s;
    __syncthreads();
    for (int off = 128; off > 0; off >>= 1) {
        if (tid < off) red[tid] += red[tid + off];
        __syncthreads();
    }
    if (tid == 0) atomicAdd(&sums[2], (double)red[0]);
}

// ---------------- finalize: KL, perplexity, total loss ----------------
__global__ void vq_finalize_kernel(const unsigned* __restrict__ counts,
                                   const double* __restrict__ sums,
                                   float* __restrict__ out_scalars) {
    __shared__ double sred[256];
    int tid = threadIdx.x;
    double t = 0.0;
    for (int k = tid; k < KCODES; k += 256) t += (double)counts[k];
    sred[tid] = t; __syncthreads();
    for (int off = 128; off > 0; off >>= 1) {
        if (tid < off) sred[tid] += sred[tid + off];
        __syncthreads();
    }
    double total = sred[0];
    __syncthreads();

    const double eps = 1e-8, tunif = 1.0 / (double)KCODES;
    double klsum = 0.0, plogpsum = 0.0;
    for (int k = tid; k < KCODES; k += 256) {
        double p = (double)counts[k] / total;
        klsum += (p + eps) * log((p + eps) / (tunif + eps));
        if (p > 0.0) plogpsum += p * log(p);
    }
    sred[tid] = klsum; __syncthreads();
    for (int off = 128; off > 0; off >>= 1) {
        if (tid < off) sred[tid] += sred[tid + off];
        __syncthreads();
    }
    klsum = sred[0];
    __syncthreads();
    sred[tid] = plogpsum; __syncthreads();
    for (int off = 128; off > 0; off >>= 1) {
        if (tid < off) sred[tid] += sred[tid + off];
        __syncthreads();
    }
    plogpsum = sred[0];

    if (tid == 0) {
        float mse = (float)(sums[0] / (double)((size_t)NROWS * DIM));
        float vq = mse + 0.25f * mse;                       // q_latent + COST*e_latent (equal in value)
        float kl = fminf((float)klsum, 100.0f);
        float l2 = fminf((float)(sums[1] / (double)KCODES), 10.0f);
        float orth = fminf((float)(sums[2] / ((double)KCODES * (double)KCODES)), 10.0f);
        float reg = l2 + orth;
        float total_loss = fminf(vq + 0.1f * kl + 0.01f * reg, 100.0f);
        out_scalars[0] = total_loss;
        out_scalars[1] = (float)exp(-plogpsum);
    }
}

extern "C" void kernel_launch(void* const* d_in, const int* in_sizes, int n_in,
                              void* d_out, int out_size, void* d_ws, size_t ws_size,
                              hipStream_t stream) {
    const float* x   = (const float*)d_in[0];   // (16,4096,256) f32
    const float* emb = (const float*)d_in[1];   // (2048,256)   f32
    float* out = (float*)d_out;

    char* ws = (char*)d_ws;
    float*    c      = (float*)(ws + WS_C);
    float*    invn   = (float*)(ws + WS_INV);
    unsigned* counts = (unsigned*)(ws + WS_COUNTS);
    double*   sums   = (double*)(ws + WS_SUMS);
    float*    x2g    = (float*)(ws + WS_X2);

    float* outq        = out;                 // quantized_st
    float* out_scalars = out + Q_OFF;         // loss, perplexity
    float* idx_f       = out + Q_OFF + 2;     // idx as float

    vq_init_kernel<<<1, 256, 0, stream>>>(counts, sums);
    vq_prep_kernel<<<KCODES, 64, 0, stream>>>(emb, c, invn, sums);
    vq_x2_kernel<<<NROWS / 256, 256, 0, stream>>>(x, x2g);
    vq_argmin_kernel<<<NROWS / BM, 256, 81920, stream>>>(x, emb, c, x2g, idx_f, counts);
    vq_gather_kernel<<<(NROWS * DIM / 4) / 256, 256, 0, stream>>>(x, emb, idx_f, outq, sums);
    vq_sim_kernel<<<(KCODES / 64) * (KCODES / 64), 256, 0, stream>>>(emb, invn, sums);
    vq_finalize_kernel<<<1, 256, 0, stream>>>(counts, sums, out_scalars);
}